// Round 14
// baseline (270.950 us; speedup 1.0000x reference)
//
#include <hip/hip_runtime.h>
#include <hip/hip_bf16.h>

#define V_ 100000
#define E_ 256
#define H_ 512
#define L_ 50000
#define S_ 512
#define T_ 64
#define NB_ 782        // ceil(L/64)
#define NBP_ 784
#define NWG_ 32

typedef short bf16x8 __attribute__((ext_vector_type(8)));
typedef float f32x4 __attribute__((ext_vector_type(4)));

__device__ __forceinline__ float sigm(float x){ return 1.0f/(1.0f+__expf(-x)); }
__device__ __forceinline__ float tanh_fast(float x){
    x = fminf(fmaxf(x, -15.f), 15.f);
    float e = __expf(2.f * x);
    return __fdividef(e - 1.f, e + 1.f);
}
__device__ __forceinline__ unsigned bf16rne(float x){
    unsigned u = __float_as_uint(x);
    return (u + 0x7fffu + ((u >> 16) & 1u)) >> 16;
}
__device__ __forceinline__ float bcast(float v, int l){
    return __uint_as_float(__builtin_amdgcn_readlane(__float_as_uint(v), l));
}

// ---------------- K3: fused attn + gatepre + persistent LSTM ----------------
// 32 WGs x 512 thr. Phase1: attn for t=2wg,2wg+1 -> ctx_g (agent stores,
// sentinel-flagged). Phase2: per-WG A_pre slice via W_ih in AGPRs + ctx poll,
// written straight to LDS A_l. Phase3: R11 LSTM loop (W_hh in AGPRs, h poll).
#define ST(i, val) asm volatile("v_accvgpr_write_b32 %0, %1" : "=a"(g##i) : "v"(val));
#define STQ(q,i0,i1,i2,i3) { float4 v_ = wsrc[q]; ST(i0,v_.x) ST(i1,v_.y) ST(i2,v_.z) ST(i3,v_.w) }
#define STJ(i, val) asm volatile("v_accvgpr_write_b32 %0, %1" : "=a"(j##i) : "v"(val));
#define STJQ(q,i0,i1,i2,i3) { float4 v_ = wsrc2[q]; STJ(i0,v_.x) STJ(i1,v_.y) STJ(i2,v_.z) STJ(i3,v_.w) }
#define RD1(i) float wv##i; asm volatile("v_accvgpr_read_b32 %0, %1" : "=v"(wv##i) : "a"(g##i));
#define RD4(i0,i1,i2,i3) RD1(i0) RD1(i1) RD1(i2) RD1(i3)
#define FMA4(i0,i1,i2,i3) \
    a0 += wv##i0 * bcast(hv, i0); a1 += wv##i1 * bcast(hv, i1); \
    a2 += wv##i2 * bcast(hv, i2); a3 += wv##i3 * bcast(hv, i3);
#define MJ4(i0,i1,i2,i3) { float w0_,w1_,w2_,w3_; \
  asm volatile("v_accvgpr_read_b32 %0, %1" : "=v"(w0_) : "a"(j##i0)); \
  asm volatile("v_accvgpr_read_b32 %0, %1" : "=v"(w1_) : "a"(j##i1)); \
  asm volatile("v_accvgpr_read_b32 %0, %1" : "=v"(w2_) : "a"(j##i2)); \
  asm volatile("v_accvgpr_read_b32 %0, %1" : "=v"(w3_) : "a"(j##i3)); \
  a0 += w0_ * bcast(cv, i0); a1 += w1_ * bcast(cv, i1); \
  a2 += w2_ * bcast(cv, i2); a3 += w3_ * bcast(cv, i3); }

__global__ __launch_bounds__(512, 1) void k_fused(
    const float* __restrict__ enc, const float* __restrict__ emb,
    const float* __restrict__ W_attn, const float* __restrict__ b_attn,
    const int* __restrict__ word_inputs,
    const float* __restrict__ W_ih, const float* __restrict__ b_ih,
    const float* __restrict__ b_hh, const float* __restrict__ W_hh,
    const float* __restrict__ h0, const float* __restrict__ c0,
    float* __restrict__ ctx_g, float* __restrict__ h_buf)
{
    __shared__ float A_l[T_ * 64];      // [t][r]
    __shared__ float red[2][8][64];     // [parity][ks][r]
    __shared__ float e_l2[512];         // [2][256]
    __shared__ float q_l2[1024];        // [2][512]
    __shared__ float sc2[1024];         // [2][512]
    __shared__ float red8[16];          // [2][8]

    const int tid = threadIdx.x, wg = blockIdx.x;
    const int lane = tid & 63;
    const int ks   = tid >> 6;
    const int base = wg * 16;
    const int G = ((lane >> 4) << 9) + base + (lane & 15);  // global gate row

    // ---- W_hh slice -> AGPRs g0..g63; W_ih slice -> AGPRs j0..j63 ----
    float g0,g1,g2,g3,g4,g5,g6,g7,g8,g9,g10,g11,g12,g13,g14,g15;
    float g16,g17,g18,g19,g20,g21,g22,g23,g24,g25,g26,g27,g28,g29,g30,g31;
    float g32,g33,g34,g35,g36,g37,g38,g39,g40,g41,g42,g43,g44,g45,g46,g47;
    float g48,g49,g50,g51,g52,g53,g54,g55,g56,g57,g58,g59,g60,g61,g62,g63;
    float j0,j1,j2,j3,j4,j5,j6,j7,j8,j9,j10,j11,j12,j13,j14,j15;
    float j16,j17,j18,j19,j20,j21,j22,j23,j24,j25,j26,j27,j28,j29,j30,j31;
    float j32,j33,j34,j35,j36,j37,j38,j39,j40,j41,j42,j43,j44,j45,j46,j47;
    float j48,j49,j50,j51,j52,j53,j54,j55,j56,j57,j58,j59,j60,j61,j62,j63;
    {
        const float4* wsrc = (const float4*)(W_hh + (long)G * H_ + ks * 64);
        STQ(0,0,1,2,3)     STQ(1,4,5,6,7)     STQ(2,8,9,10,11)   STQ(3,12,13,14,15)
        STQ(4,16,17,18,19) STQ(5,20,21,22,23) STQ(6,24,25,26,27) STQ(7,28,29,30,31)
        STQ(8,32,33,34,35) STQ(9,36,37,38,39) STQ(10,40,41,42,43)STQ(11,44,45,46,47)
        STQ(12,48,49,50,51)STQ(13,52,53,54,55)STQ(14,56,57,58,59)STQ(15,60,61,62,63)
    }
    {
        const float4* wsrc2 = (const float4*)(W_ih + (long)G * H_ + ks * 64);
        STJQ(0,0,1,2,3)     STJQ(1,4,5,6,7)     STJQ(2,8,9,10,11)   STJQ(3,12,13,14,15)
        STJQ(4,16,17,18,19) STJQ(5,20,21,22,23) STJQ(6,24,25,26,27) STJQ(7,28,29,30,31)
        STJQ(8,32,33,34,35) STJQ(9,36,37,38,39) STJQ(10,40,41,42,43)STJQ(11,44,45,46,47)
        STJQ(12,48,49,50,51)STJQ(13,52,53,54,55)STJQ(14,56,57,58,59)STJQ(15,60,61,62,63)
    }

    float c_reg = 0.f;
    if (tid < 16) c_reg = c0[base + tid];
    float bb = 0.f;
    if (tid < 64) bb = b_ih[G] + b_hh[G];

    const unsigned SENT = 0xFFFFFFFFu;

    // ================= Phase 1: attention for t0, t1 =================
    {
        const int t0 = wg * 2, t1 = wg * 2 + 1;
        const int w0i = word_inputs[t0], w1i = word_inputs[t1];
        if (tid < 256) e_l2[tid] = emb[(long)w0i * E_ + tid];
        else           e_l2[tid] = emb[(long)w1i * E_ + (tid - 256)];
        __syncthreads();

        // q[r] for both t (r = tid)
        {
            const float4* wrow = (const float4*)(W_attn + tid * E_);
            const float4* e0p = (const float4*)e_l2;
            const float4* e1p = (const float4*)(e_l2 + 256);
            float acc0 = b_attn[tid], acc1 = acc0;
            #pragma unroll 8
            for (int j2 = 0; j2 < E_ / 4; ++j2) {
                float4 w = wrow[j2], a = e0p[j2], b = e1p[j2];
                acc0 += w.x*a.x + w.y*a.y + w.z*a.z + w.w*a.w;
                acc1 += w.x*b.x + w.y*b.y + w.z*b.z + w.w*b.w;
            }
            q_l2[tid] = acc0; q_l2[512 + tid] = acc1;
        }
        __syncthreads();

        // scores[s] for both t (s = tid)
        float acc0 = 0.f, acc1 = 0.f;
        {
            const float4* er = (const float4*)(enc + tid * H_);
            const float4* q0p = (const float4*)q_l2;
            const float4* q1p = (const float4*)(q_l2 + 512);
            #pragma unroll 8
            for (int j2 = 0; j2 < H_ / 4; ++j2) {
                float4 e = er[j2], a = q0p[j2], b = q1p[j2];
                acc0 += e.x*a.x + e.y*a.y + e.z*a.z + e.w*a.w;
                acc1 += e.x*b.x + e.y*b.y + e.z*b.z + e.w*b.w;
            }
        }
        // softmax over 512 (8 waves)
        float m0 = acc0, m1 = acc1;
        for (int off = 32; off; off >>= 1) {
            m0 = fmaxf(m0, __shfl_down(m0, off));
            m1 = fmaxf(m1, __shfl_down(m1, off));
        }
        if (lane == 0) { red8[ks] = m0; red8[8 + ks] = m1; }
        __syncthreads();
        float M0 = red8[0], M1 = red8[8];
        #pragma unroll
        for (int i2 = 1; i2 < 8; ++i2) {
            M0 = fmaxf(M0, red8[i2]); M1 = fmaxf(M1, red8[8 + i2]);
        }
        float e0v = __expf(acc0 - M0), e1v = __expf(acc1 - M1);
        sc2[tid] = e0v; sc2[512 + tid] = e1v;
        float s0 = e0v, s1 = e1v;
        for (int off = 32; off; off >>= 1) {
            s0 += __shfl_down(s0, off);
            s1 += __shfl_down(s1, off);
        }
        __syncthreads();                 // red8(M) reads done
        if (lane == 0) { red8[ks] = s0; red8[8 + ks] = s1; }
        __syncthreads();
        float S0 = 0.f, S1 = 0.f;
        #pragma unroll
        for (int i2 = 0; i2 < 8; ++i2) { S0 += red8[i2]; S1 += red8[8 + i2]; }
        float inv0 = 1.f / S0, inv1 = 1.f / S1;

        // ctx[h] for both t (h = tid); enc column reads coalesced across lanes
        float c0a = 0.f, c1a = 0.f;
        #pragma unroll 4
        for (int s = 0; s < S_; ++s) {
            float ev = enc[s * H_ + tid];
            c0a += sc2[s] * ev;
            c1a += sc2[512 + s] * ev;
        }
        c0a *= inv0; c1a *= inv1;
        __hip_atomic_store((unsigned*)ctx_g + t0 * H_ + tid, __float_as_uint(c0a),
                           __ATOMIC_RELAXED, __HIP_MEMORY_SCOPE_AGENT);
        __hip_atomic_store((unsigned*)ctx_g + t1 * H_ + tid, __float_as_uint(c1a),
                           __ATOMIC_RELAXED, __HIP_MEMORY_SCOPE_AGENT);
    }

    // ================= Phase 2: A_pre slice -> LDS A_l =================
    for (int t = 0; t < T_; ++t) {
        float cv;
        {
            const unsigned* cb = (const unsigned*)ctx_g + t * H_ + ks * 64;
            unsigned u = __hip_atomic_load(cb + lane, __ATOMIC_RELAXED,
                                           __HIP_MEMORY_SCOPE_AGENT);
            while (u == SENT) {
                __builtin_amdgcn_s_sleep(1);
                u = __hip_atomic_load(cb + lane, __ATOMIC_RELAXED,
                                      __HIP_MEMORY_SCOPE_AGENT);
            }
            cv = __uint_as_float(u);
        }
        float a0 = 0.f, a1 = 0.f, a2 = 0.f, a3 = 0.f;
        MJ4(0,1,2,3)     MJ4(4,5,6,7)     MJ4(8,9,10,11)   MJ4(12,13,14,15)
        MJ4(16,17,18,19) MJ4(20,21,22,23) MJ4(24,25,26,27) MJ4(28,29,30,31)
        MJ4(32,33,34,35) MJ4(36,37,38,39) MJ4(40,41,42,43) MJ4(44,45,46,47)
        MJ4(48,49,50,51) MJ4(52,53,54,55) MJ4(56,57,58,59) MJ4(60,61,62,63)
        red[t & 1][ks][lane] = (a0 + a1) + (a2 + a3);
        __syncthreads();
        if (ks == 0) {
            float s = bb;
            #pragma unroll
            for (int k2 = 0; k2 < 8; ++k2) s += red[t & 1][k2][lane];
            A_l[t * 64 + lane] = s;
        }
    }

    // ================= Phase 3: LSTM recurrence (R11) =================
    for (int t = 0; t < T_; ++t) {
        RD4(0,1,2,3)     RD4(4,5,6,7)     RD4(8,9,10,11)   RD4(12,13,14,15)
        RD4(16,17,18,19) RD4(20,21,22,23) RD4(24,25,26,27) RD4(28,29,30,31)
        RD4(32,33,34,35) RD4(36,37,38,39) RD4(40,41,42,43) RD4(44,45,46,47)
        RD4(48,49,50,51) RD4(52,53,54,55) RD4(56,57,58,59) RD4(60,61,62,63)
        __builtin_amdgcn_sched_barrier(0);

        float hv;
        if (t == 0) {
            hv = h0[ks * 64 + lane];
        } else {
            const unsigned* hb = (const unsigned*)h_buf + (t - 1) * H_ + ks * 64;
            unsigned u = __hip_atomic_load(hb + lane, __ATOMIC_RELAXED,
                                           __HIP_MEMORY_SCOPE_AGENT);
            while (u == SENT) {
                __builtin_amdgcn_s_sleep(1);
                u = __hip_atomic_load(hb + lane, __ATOMIC_RELAXED,
                                      __HIP_MEMORY_SCOPE_AGENT);
            }
            hv = __uint_as_float(u);
        }

        float a0 = 0.f, a1 = 0.f, a2 = 0.f, a3 = 0.f;
        FMA4(0,1,2,3)     FMA4(4,5,6,7)     FMA4(8,9,10,11)   FMA4(12,13,14,15)
        FMA4(16,17,18,19) FMA4(20,21,22,23) FMA4(24,25,26,27) FMA4(28,29,30,31)
        FMA4(32,33,34,35) FMA4(36,37,38,39) FMA4(40,41,42,43) FMA4(44,45,46,47)
        FMA4(48,49,50,51) FMA4(52,53,54,55) FMA4(56,57,58,59) FMA4(60,61,62,63)
        red[t & 1][ks][lane] = (a0 + a1) + (a2 + a3);
        __syncthreads();

        if (ks == 0) {
            float s = A_l[t * 64 + lane];
            #pragma unroll
            for (int k2 = 0; k2 < 8; ++k2) s += red[t & 1][k2][lane];
            float gf_ = __shfl_down(s, 16);
            float gg_ = __shfl_down(s, 32);
            float go_ = __shfl_down(s, 48);
            if (lane < 16) {
                float gi = sigm(s);
                float gf = sigm(gf_);
                float gg = tanh_fast(gg_);
                float go = sigm(go_);
                float c2 = gf * c_reg + gi * gg;
                c_reg = c2;
                float h2 = go * tanh_fast(c2);
                __hip_atomic_store((unsigned*)h_buf + t * H_ + base + lane,
                                   __float_as_uint(h2),
                                   __ATOMIC_RELAXED, __HIP_MEMORY_SCOPE_AGENT);
            }
        }
    }
}

// ---------------- K4: MFMA W_out GEMM + per-block softmax partials ----------
__global__ __launch_bounds__(256) void k_out(
    const float* __restrict__ W_out, const float* __restrict__ b_out,
    const float* __restrict__ h_buf, const int* __restrict__ labels,
    float* __restrict__ pm, float* __restrict__ ps, float* __restrict__ ll)
{
    __shared__ __align__(16) unsigned char smem[65536];
    const int tid = threadIdx.x;
    const int r0 = blockIdx.x * 64;
    const int lane = tid & 63, w = tid >> 6;
    const int g = lane >> 4, li = lane & 15;

    for (int i = 0; i < 32; ++i) {
        int p = tid + i * 256;           // float4 idx over [64][128]
        int t = p >> 7, k4 = p & 127;
        float4 v = ((const float4*)h_buf)[p];
        unsigned p01 = bf16rne(v.x) | (bf16rne(v.y) << 16);
        unsigned p23 = bf16rne(v.z) | (bf16rne(v.w) << 16);
        unsigned byte = (unsigned)(t * 1024 + k4 * 8) ^ ((unsigned)(t & 7) << 4);
        *(uint2*)(smem + byte) = make_uint2(p01, p23);
    }

    f32x4 acc0 = {0.f,0.f,0.f,0.f}, acc1 = {0.f,0.f,0.f,0.f};
    f32x4 acc2 = {0.f,0.f,0.f,0.f}, acc3 = {0.f,0.f,0.f,0.f};
    __syncthreads();

    int rrow = r0 + w * 16 + li;
    int rw = rrow < L_ ? rrow : (L_ - 1);
    const float* ap = W_out + (long)rw * H_ + g * 8;

    #pragma unroll
    for (int kk = 0; kk < 16; ++kk) {
        float4 va = *(const float4*)(ap + kk * 32);
        float4 vb = *(const float4*)(ap + kk * 32 + 4);
        union { unsigned u[4]; bf16x8 v; } A;
        A.u[0] = bf16rne(va.x) | (bf16rne(va.y) << 16);
        A.u[1] = bf16rne(va.z) | (bf16rne(va.w) << 16);
        A.u[2] = bf16rne(vb.x) | (bf16rne(vb.y) << 16);
        A.u[3] = bf16rne(vb.z) | (bf16rne(vb.w) << 16);

        #pragma unroll
        for (int nt = 0; nt < 4; ++nt) {
            int t = nt * 16 + li;
            unsigned byte = (unsigned)(t * 1024 + kk * 64 + g * 16)
                          ^ ((unsigned)(t & 7) << 4);
            bf16x8 B = *(const bf16x8*)(smem + byte);
            f32x4* accp = (nt == 0) ? &acc0 : (nt == 1) ? &acc1
                        : (nt == 2) ? &acc2 : &acc3;
            *accp = __builtin_amdgcn_mfma_f32_16x16x32_bf16(A.v, B, *accp, 0, 0, 0);
        }
    }
    __syncthreads();

    float* lg   = (float*)smem;
    float* redb = (float*)(smem + 64 * 65 * 4);
    float* gmax = redb + 256;

    #pragma unroll
    for (int nt = 0; nt < 4; ++nt) {
        const f32x4 a = (nt == 0) ? acc0 : (nt == 1) ? acc1
                      : (nt == 2) ? acc2 : acc3;
        int t = nt * 16 + li;
        #pragma unroll
        for (int q = 0; q < 4; ++q) {
            int rloc = w * 16 + g * 4 + q;
            int r = r0 + rloc;
            float v = -1e30f;
            if (r < L_) v = a[q] + b_out[r];
            lg[rloc * 65 + t] = v;
        }
    }
    __syncthreads();

    const int t = tid & 63, part = tid >> 6;
    float m = -1e30f;
    #pragma unroll
    for (int r16 = 0; r16 < 16; ++r16)
        m = fmaxf(m, lg[(part*16 + r16)*65 + t]);
    redb[part*64 + t] = m;
    __syncthreads();
    if (part == 0)
        gmax[t] = fmaxf(fmaxf(redb[t], redb[64+t]), fmaxf(redb[128+t], redb[192+t]));
    __syncthreads();
    float gm = gmax[t];
    float s = 0.f;
    #pragma unroll
    for (int r16 = 0; r16 < 16; ++r16)
        s += __expf(lg[(part*16 + r16)*65 + t] - gm);
    __syncthreads();
    redb[part*64 + t] = s;
    __syncthreads();
    if (part == 0) {
        pm[t * NBP_ + blockIdx.x] = gm;
        ps[t * NBP_ + blockIdx.x] = redb[t] + redb[64+t] + redb[128+t] + redb[192+t];
        int lb = labels[t];
        if (lb >= r0 && lb < r0 + 64) ll[t] = lg[(lb - r0)*65 + t];
    }
}

// ---------------- K5: combine partials, NLL, total loss ---------------------
__global__ __launch_bounds__(256) void k_final(
    const float* __restrict__ pm, const float* __restrict__ ps,
    const float* __restrict__ ll, const int* __restrict__ labels,
    float* __restrict__ out)
{
    __shared__ float rbuf[8];
    const int t = blockIdx.x, tid = threadIdx.x;
    float m = -1e30f;
    for (int b = tid; b < NB_; b += 256) m = fmaxf(m, pm[t * NBP_ + b]);
    for (int off = 32; off; off >>= 1) m = fmaxf(m, __shfl_down(m, off));
    if ((tid & 63) == 0) rbuf[tid >> 6] = m;
    __syncthreads();
    if (tid == 0) rbuf[4] = fmaxf(fmaxf(rbuf[0], rbuf[1]), fmaxf(rbuf[2], rbuf[3]));
    __syncthreads();
    float M = rbuf[4];
    __syncthreads();
    float s = 0.f;
    for (int b = tid; b < NB_; b += 256)
        s += ps[t * NBP_ + b] * __expf(pm[t * NBP_ + b] - M);
    for (int off = 32; off; off >>= 1) s += __shfl_down(s, off);
    if ((tid & 63) == 0) rbuf[tid >> 6] = s;
    __syncthreads();
    if (tid == 0) {
        float S = rbuf[0] + rbuf[1] + rbuf[2] + rbuf[3];
        int lb = labels[t];
        if (lb != 0) {
            float loss = -(ll[t] - M - __logf(S));
            atomicAdd(out, loss);
        }
    }
}

extern "C" void kernel_launch(void* const* d_in, const int* in_sizes, int n_in,
                              void* d_out, int out_size, void* d_ws, size_t ws_size,
                              hipStream_t stream)
{
    (void)in_sizes; (void)n_in; (void)out_size; (void)ws_size;
    const float* enc    = (const float*)d_in[0];
    const float* h0     = (const float*)d_in[1];
    const float* c0     = (const float*)d_in[2];
    const float* emb    = (const float*)d_in[3];
    const float* W_attn = (const float*)d_in[4];
    const float* b_attn = (const float*)d_in[5];
    const float* W_ih   = (const float*)d_in[6];
    const float* W_hh   = (const float*)d_in[7];
    const float* b_ih   = (const float*)d_in[8];
    const float* b_hh   = (const float*)d_in[9];
    const float* W_out  = (const float*)d_in[10];
    const float* b_out  = (const float*)d_in[11];
    const int* widx     = (const int*)d_in[12];
    const int* labels   = (const int*)d_in[13];
    float* out = (float*)d_out;

    char* ws = (char*)d_ws;
    float* h_buf = (float*)(ws + 0);          // 131072
    float* ctx_g = (float*)(ws + 131072);     // 131072  (adjacent: one memset)
    float* pm    = (float*)(ws + 262144);     // 200704
    float* ps    = (float*)(ws + 462848);     // 200704
    float* ll    = (float*)(ws + 663552);     // 256

    hipMemsetAsync(h_buf, 0xFF, 2 * T_ * H_ * sizeof(float), stream); // h_buf+ctx_g sentinels
    hipMemsetAsync(out, 0, sizeof(float), stream);

    k_fused<<<NWG_, 512, 0, stream>>>(enc, emb, W_attn, b_attn, widx,
                                      W_ih, b_ih, b_hh, W_hh, h0, c0,
                                      ctx_g, h_buf);
    k_out<<<NB_, 256, 0, stream>>>(W_out, b_out, h_buf, labels, pm, ps, ll);
    k_final<<<T_, 256, 0, stream>>>(pm, ps, ll, labels, out);
}

// Round 15
// 238.792 us; speedup vs baseline: 1.1347x; 1.1347x over previous
//
#include <hip/hip_runtime.h>
#include <hip/hip_bf16.h>

#define V_ 100000
#define E_ 256
#define H_ 512
#define L_ 50000
#define S_ 512
#define T_ 64
#define NB_ 782        // ceil(L/64)
#define NBP_ 784
#define NWG_ 32

typedef short bf16x8 __attribute__((ext_vector_type(8)));
typedef float f32x4 __attribute__((ext_vector_type(4)));

__device__ __forceinline__ float sigm(float x){ return 1.0f/(1.0f+__expf(-x)); }
__device__ __forceinline__ float tanh_fast(float x){
    x = fminf(fmaxf(x, -15.f), 15.f);
    float e = __expf(2.f * x);
    return __fdividef(e - 1.f, e + 1.f);
}
__device__ __forceinline__ unsigned bf16rne(float x){
    unsigned u = __float_as_uint(x);
    return (u + 0x7fffu + ((u >> 16) & 1u)) >> 16;
}
__device__ __forceinline__ float bcast(float v, int l){
    return __uint_as_float(__builtin_amdgcn_readlane(__float_as_uint(v), l));
}

// ---------------- K1: attention, wave-cooperative coalesced dots ------------
// 64 blocks (one per t) x 512 thr. Every matrix-row dot is done by a full
// wave with coalesced float4 loads + shfl_xor butterfly reduce.
__global__ __launch_bounds__(512) void k_attn2(
    const float* __restrict__ enc, const float* __restrict__ emb,
    const float* __restrict__ W_attn, const float* __restrict__ b_attn,
    const int* __restrict__ word_inputs, float* __restrict__ ctx_out)
{
    __shared__ float e_l[E_];
    __shared__ float q_l[H_];
    __shared__ float sc[S_];
    __shared__ float red8[8];
    const int t = blockIdx.x, tid = threadIdx.x;
    const int lane = tid & 63, wv = tid >> 6;
    const int widx = word_inputs[t];

    if (tid < E_) e_l[tid] = emb[(long)widx * E_ + tid];
    __syncthreads();

    // ---- q[r] = W_attn[r]·e + b_attn[r]; wave wv owns rows wv*64..+64 ----
    {
        float4 e4 = *(const float4*)(e_l + lane * 4);      // 256 = 64 lanes x 4
        float b_pre = b_attn[wv * 64 + lane];
        #pragma unroll 2
        for (int i = 0; i < 64; ++i) {
            int r = wv * 64 + i;
            float4 w = *(const float4*)(W_attn + (long)r * E_ + lane * 4);
            float p = w.x*e4.x + w.y*e4.y + w.z*e4.z + w.w*e4.w;
            #pragma unroll
            for (int off = 32; off; off >>= 1) p += __shfl_xor(p, off);
            if (lane == i) q_l[r] = p + b_pre;             // all lanes hold p
        }
    }
    __syncthreads();

    // ---- scores[s] = enc[s]·q; wave wv owns rows wv*64..+64 ----
    {
        float4 qa = *(const float4*)(q_l + lane * 8);      // 512 = 64 lanes x 8
        float4 qb = *(const float4*)(q_l + lane * 8 + 4);
        #pragma unroll 2
        for (int i = 0; i < 64; ++i) {
            int s = wv * 64 + i;
            const float* er = enc + (long)s * H_ + lane * 8;
            float4 ea = *(const float4*)er;
            float4 eb = *(const float4*)(er + 4);
            float p = ea.x*qa.x + ea.y*qa.y + ea.z*qa.z + ea.w*qa.w
                    + eb.x*qb.x + eb.y*qb.y + eb.z*qb.z + eb.w*qb.w;
            #pragma unroll
            for (int off = 32; off; off >>= 1) p += __shfl_xor(p, off);
            if (lane == i) sc[s] = p;
        }
    }
    __syncthreads();

    // ---- softmax over 512 (thread tid owns sc[tid]) ----
    float v = sc[tid];
    float m = v;
    #pragma unroll
    for (int off = 32; off; off >>= 1) m = fmaxf(m, __shfl_xor(m, off));
    if (lane == 0) red8[wv] = m;
    __syncthreads();
    float M = red8[0];
    #pragma unroll
    for (int i = 1; i < 8; ++i) M = fmaxf(M, red8[i]);
    float ev = __expf(v - M);
    float ssum = ev;
    #pragma unroll
    for (int off = 32; off; off >>= 1) ssum += __shfl_xor(ssum, off);
    __syncthreads();                    // red8(max) reads done
    sc[tid] = ev;
    if (lane == 0) red8[wv] = ssum;
    __syncthreads();
    float S = 0.f;
    #pragma unroll
    for (int i = 0; i < 8; ++i) S += red8[i];
    float inv = 1.0f / S;

    // ---- ctx[h] = sum_s alpha[s]*enc[s][h]; h = tid (coalesced) ----
    float acc = 0.f;
    #pragma unroll 4
    for (int s = 0; s < S_; ++s) acc += sc[s] * enc[s * H_ + tid];
    ctx_out[t * H_ + tid] = acc * inv;
}

// ---------------- K2: A[t] = W_ih @ ctx_t + b_ih + b_hh ---------------------
__global__ __launch_bounds__(256) void k_gatepre(
    const float* __restrict__ ctx, const float* __restrict__ W_ih,
    const float* __restrict__ b_ih, const float* __restrict__ b_hh,
    float* __restrict__ A_pre)
{
    __shared__ float ctx_t[H_ * 65];   // transposed [k][t], stride 65
    __shared__ float w_l[8 * H_];
    const int tid = threadIdx.x;
    const int r0 = blockIdx.x * 8;

    for (int i = 0; i < 32; ++i) {
        int p = tid + i * 256;
        int t = p >> 7, k4 = p & 127;
        float4 v = ((const float4*)ctx)[p];
        ctx_t[(k4*4+0)*65 + t] = v.x;
        ctx_t[(k4*4+1)*65 + t] = v.y;
        ctx_t[(k4*4+2)*65 + t] = v.z;
        ctx_t[(k4*4+3)*65 + t] = v.w;
    }
    for (int i = 0; i < 4; ++i) {
        int p = tid + i * 256;
        int row = p >> 7, k4 = p & 127;
        float4 v = ((const float4*)W_ih)[(r0 + row) * (H_/4) + k4];
        float* dst = &w_l[row * H_ + k4 * 4];
        dst[0]=v.x; dst[1]=v.y; dst[2]=v.z; dst[3]=v.w;
    }
    __syncthreads();

    const int t = tid & 63, half = tid >> 6;
    const float* w0 = &w_l[(half*2+0) * H_];
    const float* w1 = &w_l[(half*2+1) * H_];
    float acc0 = 0.f, acc1 = 0.f;
    #pragma unroll 4
    for (int k = 0; k < H_; ++k) {
        float cv = ctx_t[k * 65 + t];
        acc0 += w0[k] * cv;
        acc1 += w1[k] * cv;
    }
    int ra = r0 + half * 2, rb = ra + 1;
    A_pre[t * 2048 + ra] = acc0 + b_ih[ra] + b_hh[ra];
    A_pre[t * 2048 + rb] = acc1 + b_ih[rb] + b_hh[rb];
}

// ---------------- K3: persistent LSTM (32 WGs, W in AGPRs, pre-poll read) ---
#define ST(i, val) asm volatile("v_accvgpr_write_b32 %0, %1" : "=a"(g##i) : "v"(val));
#define STQ(q,i0,i1,i2,i3) { float4 v_ = wsrc[q]; ST(i0,v_.x) ST(i1,v_.y) ST(i2,v_.z) ST(i3,v_.w) }
#define RD1(i) float wv##i; asm volatile("v_accvgpr_read_b32 %0, %1" : "=v"(wv##i) : "a"(g##i));
#define RD4(i0,i1,i2,i3) RD1(i0) RD1(i1) RD1(i2) RD1(i3)
#define FMA4(i0,i1,i2,i3) \
    a0 += wv##i0 * bcast(hv, i0); a1 += wv##i1 * bcast(hv, i1); \
    a2 += wv##i2 * bcast(hv, i2); a3 += wv##i3 * bcast(hv, i3);

__global__ __launch_bounds__(512, 1) void k_lstm(
    const float* __restrict__ W_hh, const float* __restrict__ A_pre,
    const float* __restrict__ h0, const float* __restrict__ c0,
    float* __restrict__ h_buf)
{
    const int tid = threadIdx.x, wg = blockIdx.x;

    __shared__ float A_l[T_ * 64];      // [t][r]
    __shared__ float red[2][8][64];     // [parity][ks][r]

    const int base = wg * 16;
    const int lane = tid & 63;
    const int ks   = tid >> 6;
    const int G = ((lane >> 4) << 9) + base + (lane & 15);  // global gate row

    float g0,g1,g2,g3,g4,g5,g6,g7,g8,g9,g10,g11,g12,g13,g14,g15;
    float g16,g17,g18,g19,g20,g21,g22,g23,g24,g25,g26,g27,g28,g29,g30,g31;
    float g32,g33,g34,g35,g36,g37,g38,g39,g40,g41,g42,g43,g44,g45,g46,g47;
    float g48,g49,g50,g51,g52,g53,g54,g55,g56,g57,g58,g59,g60,g61,g62,g63;
    {
        const float4* wsrc = (const float4*)(W_hh + (long)G * H_ + ks * 64);
        STQ(0,0,1,2,3)     STQ(1,4,5,6,7)     STQ(2,8,9,10,11)   STQ(3,12,13,14,15)
        STQ(4,16,17,18,19) STQ(5,20,21,22,23) STQ(6,24,25,26,27) STQ(7,28,29,30,31)
        STQ(8,32,33,34,35) STQ(9,36,37,38,39) STQ(10,40,41,42,43)STQ(11,44,45,46,47)
        STQ(12,48,49,50,51)STQ(13,52,53,54,55)STQ(14,56,57,58,59)STQ(15,60,61,62,63)
    }

    for (int i = 0; i < 8; ++i) {
        int p = tid + i * 512;          // [0, 4096)
        int tt = p >> 6, rr = p & 63;
        A_l[p] = A_pre[tt * 2048 + ((rr >> 4) << 9) + base + (rr & 15)];
    }
    float c_reg = 0.f;
    if (tid < 16) c_reg = c0[base + tid];
    __syncthreads();

    const unsigned SENT = 0xFFFFFFFFu;

    for (int t = 0; t < T_; ++t) {
        RD4(0,1,2,3)     RD4(4,5,6,7)     RD4(8,9,10,11)   RD4(12,13,14,15)
        RD4(16,17,18,19) RD4(20,21,22,23) RD4(24,25,26,27) RD4(28,29,30,31)
        RD4(32,33,34,35) RD4(36,37,38,39) RD4(40,41,42,43) RD4(44,45,46,47)
        RD4(48,49,50,51) RD4(52,53,54,55) RD4(56,57,58,59) RD4(60,61,62,63)
        __builtin_amdgcn_sched_barrier(0);

        float hv;
        if (t == 0) {
            hv = h0[ks * 64 + lane];
        } else {
            const unsigned* hb = (const unsigned*)h_buf + (t - 1) * H_ + ks * 64;
            unsigned u = __hip_atomic_load(hb + lane, __ATOMIC_RELAXED,
                                           __HIP_MEMORY_SCOPE_AGENT);
            while (u == SENT) {
                __builtin_amdgcn_s_sleep(1);
                u = __hip_atomic_load(hb + lane, __ATOMIC_RELAXED,
                                      __HIP_MEMORY_SCOPE_AGENT);
            }
            hv = __uint_as_float(u);
        }

        float a0 = 0.f, a1 = 0.f, a2 = 0.f, a3 = 0.f;
        FMA4(0,1,2,3)     FMA4(4,5,6,7)     FMA4(8,9,10,11)   FMA4(12,13,14,15)
        FMA4(16,17,18,19) FMA4(20,21,22,23) FMA4(24,25,26,27) FMA4(28,29,30,31)
        FMA4(32,33,34,35) FMA4(36,37,38,39) FMA4(40,41,42,43) FMA4(44,45,46,47)
        FMA4(48,49,50,51) FMA4(52,53,54,55) FMA4(56,57,58,59) FMA4(60,61,62,63)
        red[t & 1][ks][lane] = (a0 + a1) + (a2 + a3);
        __syncthreads();

        if (ks == 0) {
            float s = A_l[t * 64 + lane];
            #pragma unroll
            for (int k2 = 0; k2 < 8; ++k2) s += red[t & 1][k2][lane];
            float gf_ = __shfl_down(s, 16);
            float gg_ = __shfl_down(s, 32);
            float go_ = __shfl_down(s, 48);
            if (lane < 16) {
                float gi = sigm(s);
                float gf = sigm(gf_);
                float gg = tanh_fast(gg_);
                float go = sigm(go_);
                float c2 = gf * c_reg + gi * gg;
                c_reg = c2;
                float h2 = go * tanh_fast(c2);
                __hip_atomic_store((unsigned*)h_buf + t * H_ + base + lane,
                                   __float_as_uint(h2),
                                   __ATOMIC_RELAXED, __HIP_MEMORY_SCOPE_AGENT);
            }
        }
    }
}

// ---------------- K4: MFMA W_out GEMM + per-block softmax partials ----------
__global__ __launch_bounds__(256) void k_out(
    const float* __restrict__ W_out, const float* __restrict__ b_out,
    const float* __restrict__ h_buf, const int* __restrict__ labels,
    float* __restrict__ pm, float* __restrict__ ps, float* __restrict__ ll)
{
    __shared__ __align__(16) unsigned char smem[65536];
    const int tid = threadIdx.x;
    const int r0 = blockIdx.x * 64;
    const int lane = tid & 63, w = tid >> 6;
    const int g = lane >> 4, li = lane & 15;

    for (int i = 0; i < 32; ++i) {
        int p = tid + i * 256;           // float4 idx over [64][128]
        int t = p >> 7, k4 = p & 127;
        float4 v = ((const float4*)h_buf)[p];
        unsigned p01 = bf16rne(v.x) | (bf16rne(v.y) << 16);
        unsigned p23 = bf16rne(v.z) | (bf16rne(v.w) << 16);
        unsigned byte = (unsigned)(t * 1024 + k4 * 8) ^ ((unsigned)(t & 7) << 4);
        *(uint2*)(smem + byte) = make_uint2(p01, p23);
    }

    f32x4 acc0 = {0.f,0.f,0.f,0.f}, acc1 = {0.f,0.f,0.f,0.f};
    f32x4 acc2 = {0.f,0.f,0.f,0.f}, acc3 = {0.f,0.f,0.f,0.f};
    __syncthreads();

    int rrow = r0 + w * 16 + li;
    int rw = rrow < L_ ? rrow : (L_ - 1);
    const float* ap = W_out + (long)rw * H_ + g * 8;

    #pragma unroll
    for (int kk = 0; kk < 16; ++kk) {
        float4 va = *(const float4*)(ap + kk * 32);
        float4 vb = *(const float4*)(ap + kk * 32 + 4);
        union { unsigned u[4]; bf16x8 v; } A;
        A.u[0] = bf16rne(va.x) | (bf16rne(va.y) << 16);
        A.u[1] = bf16rne(va.z) | (bf16rne(va.w) << 16);
        A.u[2] = bf16rne(vb.x) | (bf16rne(vb.y) << 16);
        A.u[3] = bf16rne(vb.z) | (bf16rne(vb.w) << 16);

        #pragma unroll
        for (int nt = 0; nt < 4; ++nt) {
            int t = nt * 16 + li;
            unsigned byte = (unsigned)(t * 1024 + kk * 64 + g * 16)
                          ^ ((unsigned)(t & 7) << 4);
            bf16x8 B = *(const bf16x8*)(smem + byte);
            f32x4* accp = (nt == 0) ? &acc0 : (nt == 1) ? &acc1
                        : (nt == 2) ? &acc2 : &acc3;
            *accp = __builtin_amdgcn_mfma_f32_16x16x32_bf16(A.v, B, *accp, 0, 0, 0);
        }
    }
    __syncthreads();

    float* lg   = (float*)smem;
    float* redb = (float*)(smem + 64 * 65 * 4);
    float* gmax = redb + 256;

    #pragma unroll
    for (int nt = 0; nt < 4; ++nt) {
        const f32x4 a = (nt == 0) ? acc0 : (nt == 1) ? acc1
                      : (nt == 2) ? acc2 : acc3;
        int t = nt * 16 + li;
        #pragma unroll
        for (int q = 0; q < 4; ++q) {
            int rloc = w * 16 + g * 4 + q;
            int r = r0 + rloc;
            float v = -1e30f;
            if (r < L_) v = a[q] + b_out[r];
            lg[rloc * 65 + t] = v;
        }
    }
    __syncthreads();

    const int t = tid & 63, part = tid >> 6;
    float m = -1e30f;
    #pragma unroll
    for (int r16 = 0; r16 < 16; ++r16)
        m = fmaxf(m, lg[(part*16 + r16)*65 + t]);
    redb[part*64 + t] = m;
    __syncthreads();
    if (part == 0)
        gmax[t] = fmaxf(fmaxf(redb[t], redb[64+t]), fmaxf(redb[128+t], redb[192+t]));
    __syncthreads();
    float gm = gmax[t];
    float s = 0.f;
    #pragma unroll
    for (int r16 = 0; r16 < 16; ++r16)
        s += __expf(lg[(part*16 + r16)*65 + t] - gm);
    __syncthreads();
    redb[part*64 + t] = s;
    __syncthreads();
    if (part == 0) {
        pm[t * NBP_ + blockIdx.x] = gm;
        ps[t * NBP_ + blockIdx.x] = redb[t] + redb[64+t] + redb[128+t] + redb[192+t];
        int lb = labels[t];
        if (lb >= r0 && lb < r0 + 64) ll[t] = lg[(lb - r0)*65 + t];
    }
}

// ---------------- K5: combine partials, NLL, total loss ---------------------
__global__ __launch_bounds__(256) void k_final(
    const float* __restrict__ pm, const float* __restrict__ ps,
    const float* __restrict__ ll, const int* __restrict__ labels,
    float* __restrict__ out)
{
    __shared__ float rbuf[8];
    const int t = blockIdx.x, tid = threadIdx.x;
    float m = -1e30f;
    for (int b = tid; b < NB_; b += 256) m = fmaxf(m, pm[t * NBP_ + b]);
    for (int off = 32; off; off >>= 1) m = fmaxf(m, __shfl_down(m, off));
    if ((tid & 63) == 0) rbuf[tid >> 6] = m;
    __syncthreads();
    if (tid == 0) rbuf[4] = fmaxf(fmaxf(rbuf[0], rbuf[1]), fmaxf(rbuf[2], rbuf[3]));
    __syncthreads();
    float M = rbuf[4];
    __syncthreads();
    float s = 0.f;
    for (int b = tid; b < NB_; b += 256)
        s += ps[t * NBP_ + b] * __expf(pm[t * NBP_ + b] - M);
    for (int off = 32; off; off >>= 1) s += __shfl_down(s, off);
    if ((tid & 63) == 0) rbuf[tid >> 6] = s;
    __syncthreads();
    if (tid == 0) {
        float S = rbuf[0] + rbuf[1] + rbuf[2] + rbuf[3];
        int lb = labels[t];
        if (lb != 0) {
            float loss = -(ll[t] - M - __logf(S));
            atomicAdd(out, loss);
        }
    }
}

extern "C" void kernel_launch(void* const* d_in, const int* in_sizes, int n_in,
                              void* d_out, int out_size, void* d_ws, size_t ws_size,
                              hipStream_t stream)
{
    (void)in_sizes; (void)n_in; (void)out_size; (void)ws_size;
    const float* enc    = (const float*)d_in[0];
    const float* h0     = (const float*)d_in[1];
    const float* c0     = (const float*)d_in[2];
    const float* emb    = (const float*)d_in[3];
    const float* W_attn = (const float*)d_in[4];
    const float* b_attn = (const float*)d_in[5];
    const float* W_ih   = (const float*)d_in[6];
    const float* W_hh   = (const float*)d_in[7];
    const float* b_ih   = (const float*)d_in[8];
    const float* b_hh   = (const float*)d_in[9];
    const float* W_out  = (const float*)d_in[10];
    const float* b_out  = (const float*)d_in[11];
    const int* widx     = (const int*)d_in[12];
    const int* labels   = (const int*)d_in[13];
    float* out = (float*)d_out;

    char* ws = (char*)d_ws;
    float* ctx   = (float*)(ws + 0);          // 131072
    float* A_pre = (float*)(ws + 131072);     // 524288
    float* h_buf = (float*)(ws + 655360);     // 131072
    float* pm    = (float*)(ws + 786688);     // 200704
    float* ps    = (float*)(ws + 987392);     // 200704
    float* ll    = (float*)(ws + 1188096);    // 256

    hipMemsetAsync(h_buf, 0xFF, T_ * H_ * sizeof(float), stream);  // sentinel
    hipMemsetAsync(out, 0, sizeof(float), stream);

    k_attn2<<<T_, 512, 0, stream>>>(enc, emb, W_attn, b_attn, widx, ctx);
    k_gatepre<<<256, 256, 0, stream>>>(ctx, W_ih, b_ih, b_hh, A_pre);
    k_lstm<<<NWG_, 512, 0, stream>>>(W_hh, A_pre, h0, c0, h_buf);
    k_out<<<NB_, 256, 0, stream>>>(W_out, b_out, h_buf, labels, pm, ps, ll);
    k_final<<<T_, 256, 0, stream>>>(pm, ps, ll, labels, out);
}